// Round 20
// baseline (337.724 us; speedup 1.0000x reference)
//
#include <hip/hip_runtime.h>
#include <stdint.h>

#define NIMG 16
#define ATOT 261888
#define TOTC 4768
#define POSTN 1000
#define ROWQ 75   // qwords per suppression-matrix row (4768 bits -> 75)
#define EQCAP 8192
#define SCAP 1088  // LDS staging capacity per k_emit block (max real count ~950)
#define BPRE 24    // matrix truncation: rows < BPRE*64, col-chunks < BPRE (resolve stops at B~18)
// Exact div-free NMS predicate: RN(inter/uni) > 0.7f  <=>  inter >= DM*uni (doubles exact).
// DM = midpoint(0.7f, nextafterf(0.7f)); tie rounds to even (0x3F333334 > 0.7f) -> use >=.
#define DM 0.7000000178813934326171875

__device__ __forceinline__ unsigned sortable_u32(float f) {
  unsigned b = __float_as_uint(f);
  return (b & 0x80000000u) ? ~b : (b | 0x80000000u);
}

// ---- XLA CPU expf replica (Cephes constants, FMA as vsl.MulAdd)  [VERIFIED absmax 0.0] ----
__device__ __forceinline__ float exp_xla(float x) {
  float xc = fminf(x, 88.72283935546875f);
  xc = fmaxf(xc, -87.33654022216796875f);
  float n = floorf(fmaf(xc, 1.44269504088896341f, 0.5f));
  float r = fmaf(n, -0.693359375f, xc);
  r = fmaf(n, 2.12194440e-4f, r);
  float y = 1.9875691500e-4f;
  y = fmaf(y, r, 1.3981999507e-3f);
  y = fmaf(y, r, 8.3334519073e-3f);
  y = fmaf(y, r, 4.1665795894e-2f);
  y = fmaf(y, r, 1.6666665459e-1f);
  y = fmaf(y, r, 5.0000001201e-1f);
  float r2 = r * r;
  y = fmaf(y, r2, r);
  y = y + 1.0f;
  return ldexpf(y, (int)n);
}

__device__ __forceinline__ float sigmoid_ref(float x) {
#pragma clang fp contract(off)
  float e = exp_xla(-x);
  return 1.0f / (1.0f + e);
}

// Fine chunk mapping: 64 chunks of <=4096 elements per image over levels 0..3.
__device__ __forceinline__ void chunk_map4k(int c, int& lvl, int& start, int& cnt) {
  if (c < 48)      { lvl = 0; start = c * 4096;        cnt = 4096; }
  else if (c < 60) { lvl = 1; start = (c - 48) * 4096; cnt = 4096; }
  else if (c < 63) { lvl = 2; start = (c - 60) * 4096; cnt = 4096; }
  else             { lvl = 3; start = 0;               cnt = 3072; }
}
__constant__ int d_LO[5] = {0, 196608, 245760, 258048, 261120};
__constant__ int d_CO[5] = {0, 1000, 2000, 3000, 4000};

// ---- S0: zero hist/cnt/maxcb in one dispatch ----
__global__ void __launch_bounds__(256) k_zero(unsigned* __restrict__ hist,
                                              unsigned* __restrict__ cnt,
                                              unsigned* __restrict__ maxcb) {
  int i = blockIdx.x * 256 + threadIdx.x;
  hist[i] = 0;
  if (i < 128) cnt[i] = 0;
  if (i < 16) maxcb[i] = 0;
}

// ---- S1: per-(img,lvl) 256-bin histogram of top-8 sortable bits ----
__global__ void __launch_bounds__(256) k_hist(const float* __restrict__ obj,
                                              unsigned* __restrict__ hist) {
  int img = blockIdx.x >> 6, c = blockIdx.x & 63;
  int lvl, start, cnt;
  chunk_map4k(c, lvl, start, cnt);
  const float4* p4 = (const float4*)(obj + (size_t)img * ATOT + d_LO[lvl] + start);
  __shared__ unsigned h[256];
  h[threadIdx.x] = 0;
  __syncthreads();
  int nv = cnt >> 2;
  for (int i = threadIdx.x; i < nv; i += 256) {
    float4 v = p4[i];
    atomicAdd(&h[sortable_u32(v.x) >> 24], 1u);
    atomicAdd(&h[sortable_u32(v.y) >> 24], 1u);
    atomicAdd(&h[sortable_u32(v.z) >> 24], 1u);
    atomicAdd(&h[sortable_u32(v.w) >> 24], 1u);
  }
  __syncthreads();
  unsigned* gh = hist + (img * 4 + lvl) * 256;
  if (h[threadIdx.x]) atomicAdd(&gh[threadIdx.x], h[threadIdx.x]);
}

// ---- S2: per-(img,lvl) threshold bucket d0 + krem ----
__global__ void __launch_bounds__(64) k_thresh(const unsigned* __restrict__ hist,
                                               unsigned* __restrict__ thr) {
  int il = blockIdx.x;
  if (threadIdx.x != 0) return;
  const unsigned* h = hist + il * 256;
  unsigned krem = 1000, cum = 0;
  int d = 255;
  for (; d > 0; --d) {
    if (cum + h[d] >= krem) break;
    cum += h[d];
  }
  thr[il * 2] = (unsigned)d;
  thr[il * 2 + 1] = krem - cum;
}

// ---- S3: emit via LDS compaction + per-block bulk reservation (verified r11) ----
__global__ void __launch_bounds__(256) k_emit(const float* __restrict__ obj,
                                              const unsigned* __restrict__ thr,
                                              int* __restrict__ cand,
                                              int* __restrict__ eqbuf,
                                              unsigned* __restrict__ cnt) {
  int img = blockIdx.x / 65, c = blockIdx.x % 65;
  if (c == 64) {
    for (int i = threadIdx.x; i < 768; i += 256)
      cand[img * TOTC + d_CO[4] + i] = d_LO[4] + i;
    return;
  }
  int lvl, start, cntn;
  chunk_map4k(c, lvl, start, cntn);
  int il = img * 4 + lvl;
  unsigned d0 = thr[il * 2];
  int gbase = d_LO[lvl] + start;
  const float4* p4 = (const float4*)(obj + (size_t)img * ATOT + gbase);
  int nv = cntn >> 2;
  int cbase = img * TOTC + d_CO[lvl];

  __shared__ int gts[SCAP], eqs[SCAP];
  __shared__ int nGt, nEq, gtBase, eqBase;
  if (threadIdx.x == 0) { nGt = 0; nEq = 0; }
  __syncthreads();

  float4 v[4];
  int ni = 0;
#pragma unroll
  for (int k = 0; k < 4; ++k) {
    int i = threadIdx.x + k * 256;
    if (i < nv) { v[k] = p4[i]; ni = k + 1; }
  }
#pragma unroll
  for (int k = 0; k < 4; ++k) {
    if (k >= ni) break;
    float vv[4] = {v[k].x, v[k].y, v[k].z, v[k].w};
#pragma unroll
    for (int c4 = 0; c4 < 4; ++c4) {
      unsigned u = sortable_u32(vv[c4]);
      unsigned d = u >> 24;
      if (d >= d0) {
        int gidx = gbase + (threadIdx.x + k * 256) * 4 + c4;
        if (d > d0) {
          int p = atomicAdd(&nGt, 1);
          if (p < SCAP) gts[p] = gidx;
          else { int s = (int)atomicAdd(&cnt[il * 2], 1u); cand[cbase + s] = gidx; }
        } else {
          int p = atomicAdd(&nEq, 1);
          if (p < SCAP) eqs[p] = gidx;
          else { int e = (int)atomicAdd(&cnt[il * 2 + 1], 1u); if (e < EQCAP) eqbuf[il * EQCAP + e] = gidx; }
        }
      }
    }
  }
  __syncthreads();
  int ng = nGt < SCAP ? nGt : SCAP;
  int ne = nEq < SCAP ? nEq : SCAP;
  if (threadIdx.x == 0) {
    gtBase = (int)atomicAdd(&cnt[il * 2], (unsigned)ng);
    eqBase = (int)atomicAdd(&cnt[il * 2 + 1], (unsigned)ne);
  }
  __syncthreads();
  for (int k = threadIdx.x; k < ng; k += 256) cand[cbase + gtBase + k] = gts[k];
  for (int k = threadIdx.x; k < ne; k += 256) {
    int e = eqBase + k;
    if (e < EQCAP) eqbuf[il * EQCAP + e] = eqs[k];
  }
}

// ---- S4: refine eq-bucket with radix rounds 1-3 ----
__global__ void __launch_bounds__(256) k_refine(const float* __restrict__ obj,
                                                const unsigned* __restrict__ thr,
                                                const int* __restrict__ eqbuf,
                                                const unsigned* __restrict__ cnt,
                                                int* __restrict__ cand) {
  int il = blockIdx.x;
  int img = il >> 2, lvl = il & 3;
  unsigned pref = thr[il * 2];
  unsigned krem = thr[il * 2 + 1];
  int neq = min((int)cnt[il * 2 + 1], EQCAP);
  int cgt = (int)cnt[il * 2];
  const float* p = obj + (size_t)img * ATOT;
  const int* eq = eqbuf + il * EQCAP;
  int cbase = img * TOTC + d_CO[lvl];
  __shared__ unsigned h[256];
  __shared__ unsigned s_pref, s_krem;
  for (int round = 1; round < 4; ++round) {
    int shift = 24 - 8 * round;
    h[threadIdx.x] = 0;
    __syncthreads();
    for (int e = threadIdx.x; e < neq; e += 256) {
      unsigned u = sortable_u32(p[eq[e]]);
      if ((u >> (shift + 8)) == pref) atomicAdd(&h[(u >> shift) & 255u], 1u);
    }
    __syncthreads();
    if (threadIdx.x == 0) {
      unsigned cum = 0;
      int d = 255;
      for (; d > 0; --d) {
        if (cum + h[d] >= krem) break;
        cum += h[d];
      }
      s_pref = (pref << 8) | (unsigned)d;
      s_krem = krem - cum;
    }
    __syncthreads();
    pref = s_pref;
    krem = s_krem;
    __syncthreads();
  }
  __shared__ int cg2, ce2;
  __shared__ int eqi[1024];
  if (threadIdx.x == 0) { cg2 = 0; ce2 = 0; }
  __syncthreads();
  for (int e = threadIdx.x; e < neq; e += 256) {
    int gidx = eq[e];
    unsigned u = sortable_u32(p[gidx]);
    if (u > pref) {
      int s = atomicAdd(&cg2, 1);
      cand[cbase + cgt + s] = gidx;
    } else if (u == pref) {
      int s2 = atomicAdd(&ce2, 1);
      if (s2 < 1024) eqi[s2] = gidx;
    }
  }
  __syncthreads();
  if (threadIdx.x == 0) {
    int ne = ce2 < 1024 ? ce2 : 1024;
    int base = cgt + cg2;
    for (int r = 0; r < (int)krem; ++r) {
      int besti = -1, bestv = 0x7fffffff;
      for (int e2 = 0; e2 < ne; ++e2) {
        int v = eqi[e2];
        if (v >= 0 && v < bestv) { bestv = v; besti = e2; }
      }
      if (besti < 0) break;
      eqi[besti] = -1;
      cand[cbase + base + r] = bestv;
    }
  }
}

// ---- K2: sort each level's selected slots by (obj desc, idx asc) ----
__global__ void __launch_bounds__(1024) k_lvlsort(const float* __restrict__ obj,
                                                  int* __restrict__ cand) {
  const int KL[5] = {1000, 1000, 1000, 1000, 768};
  const int CO[5] = {0, 1000, 2000, 3000, 4000};
  int img = blockIdx.x / 5, lvl = blockIdx.x % 5;
  int k = KL[lvl];
  int cbase = img * TOTC + CO[lvl];
  int tid = threadIdx.x;
  __shared__ unsigned long long sh[1024];
  unsigned long long key = 0ull;
  if (tid < k) {
    int idx = cand[cbase + tid];
    unsigned u = sortable_u32(obj[(size_t)img * ATOT + idx]);
    key = ((unsigned long long)u << 32) | (unsigned)(0xFFFFFFFFu - (unsigned)idx);
  }
  sh[tid] = key;
  __syncthreads();
  for (int kk = 2; kk <= 1024; kk <<= 1)
    for (int j = kk >> 1; j > 0; j >>= 1) {
      int ixj = tid ^ j;
      if (ixj > tid) {
        unsigned long long a = sh[tid], b = sh[ixj];
        bool up2 = ((tid & kk) == 0);
        if ((a < b) == up2) { sh[tid] = b; sh[ixj] = a; }
      }
      __syncthreads();
    }
  if (tid < k) {
    unsigned low = (unsigned)(sh[tid] & 0xFFFFFFFFull);
    cand[cbase + tid] = (int)(0xFFFFFFFFu - low);
  }
}

// ---- K3: gather + sigmoid + BoxCoder decode + clip + valid; per-image max coord ----
__global__ void __launch_bounds__(256) k_decode(const float* __restrict__ obj,
                                                const float* __restrict__ del,
                                                const float* __restrict__ anc,
                                                const int* __restrict__ cand,
                                                float* __restrict__ boxo,
                                                float* __restrict__ keyf,
                                                unsigned* __restrict__ skey,
                                                unsigned* __restrict__ maxcb) {
#pragma clang fp contract(off)
  int img = blockIdx.x;
  int c = blockIdx.y * 256 + threadIdx.x;
  float m = 0.0f;
  if (c < TOTC) {
    int a = cand[img * TOTC + c];
    float o = obj[(size_t)img * ATOT + a];
    float s = sigmoid_ref(o);
    const float* ap = anc + (size_t)a * 4;
    float a0 = ap[0], a1 = ap[1], a2 = ap[2], a3 = ap[3];
    const float* dp = del + ((size_t)img * ATOT + (size_t)a) * 4;
    float dx = dp[0], dy = dp[1], dw = dp[2], dh = dp[3];
    float wa = a2 - a0, ha = a3 - a1;
    float cxa = a0 + 0.5f * wa, cya = a1 + 0.5f * ha;
    dw = fminf(dw, 4.135166556742356f);
    dh = fminf(dh, 4.135166556742356f);
    float cx = dx * wa + cxa;
    float cy = dy * ha + cya;
    float w = exp_xla(dw) * wa;
    float h = exp_xla(dh) * ha;
    float x1 = cx - 0.5f * w, y1 = cy - 0.5f * h;
    float x2 = cx + 0.5f * w, y2 = cy + 0.5f * h;
    x1 = fminf(fmaxf(x1, 0.0f), 1024.0f);
    x2 = fminf(fmaxf(x2, 0.0f), 1024.0f);
    y1 = fminf(fmaxf(y1, 0.0f), 1024.0f);
    y2 = fminf(fmaxf(y2, 0.0f), 1024.0f);
    float ww = x2 - x1, hh = y2 - y1;
    bool valid = (ww >= 1e-3f) && (hh >= 1e-3f) && (s >= 0.0f);
    float kf = valid ? s : -1.0f;
    float4 bx = make_float4(x1, y1, x2, y2);
    *(float4*)(boxo + (size_t)(img * TOTC + c) * 4) = bx;
    keyf[img * TOTC + c] = kf;
    skey[img * TOTC + c] = sortable_u32(kf);
    m = fmaxf(fmaxf(x1, x2), fmaxf(y1, y2));
  }
  __shared__ float red[256];
  red[threadIdx.x] = m;
  __syncthreads();
  for (int s2 = 128; s2 > 0; s2 >>= 1) {
    if (threadIdx.x < s2) red[threadIdx.x] = fmaxf(red[threadIdx.x], red[threadIdx.x + s2]);
    __syncthreads();
  }
  if (threadIdx.x == 0) atomicMax(&maxcb[img], __float_as_uint(red[0]));
}

// ---- K4 (rank-by-count): ord[rank] = slot (verified r15) ----
__global__ void __launch_bounds__(256) k_rank(const unsigned* __restrict__ skey,
                                              int* __restrict__ ord) {
  int img = blockIdx.x / 19;
  int tile = blockIdx.x % 19;
  __shared__ unsigned long long keys[TOTC];
  const unsigned* sk = skey + img * TOTC;
  for (int k = threadIdx.x; k < TOTC; k += 256)
    keys[k] = ((unsigned long long)sk[k] << 16) | (unsigned)(0xFFFF - k);
  __syncthreads();
  int i = tile * 256 + threadIdx.x;
  if (i >= TOTC) return;
  unsigned long long my = keys[i];
  int cnt = 0;
  int j = 0;
  for (; j + 8 <= TOTC; j += 8) {
#pragma unroll
    for (int u = 0; u < 8; ++u) cnt += (keys[j + u] > my) ? 1 : 0;
  }
  for (; j < TOTC; ++j) cnt += (keys[j] > my) ? 1 : 0;
  ord[img * TOTC + cnt] = i;
}

// ---- K5: build sorted records + validw (rank-space ballot) ----
__global__ void __launch_bounds__(256) k_srec(const float* __restrict__ boxo,
                                              const float* __restrict__ keyf,
                                              const int* __restrict__ ord,
                                              const unsigned* __restrict__ maxcb,
                                              float* __restrict__ srec,
                                              unsigned long long* __restrict__ validw) {
#pragma clang fp contract(off)
  int img = blockIdx.x;
  int i = blockIdx.y * 256 + threadIdx.x;
  if (i >= TOTC) return;
  int p = ord[img * TOTC + i];
  int lvl = p / 1000;
  if (lvl > 4) lvl = 4;
  float4 b = *(const float4*)(boxo + (size_t)(img * TOTC + p) * 4);
  float maxc = __uint_as_float(maxcb[img]);
  float off = (float)lvl * (maxc + 1.0f);
  float ox1 = b.x + off, oy1 = b.y + off, ox2 = b.z + off, oy2 = b.w + off;
  float area = (ox2 - ox1) * (oy2 - oy1);
  float kf = keyf[img * TOTC + p];
  float* r = srec + (size_t)(img * TOTC + i) * 12;
  r[0] = ox1; r[1] = oy1; r[2] = ox2; r[3] = oy2;
  r[4] = area; r[5] = kf;
  r[6] = b.x; r[7] = b.y; r[8] = b.z; r[9] = b.w;
  r[10] = __int_as_float(lvl); r[11] = 0.0f;
  bool valid = kf > -0.5f;
  unsigned long long vb = __ballot(valid);
  if ((threadIdx.x & 63) == 0 && (i >> 6) < ROWQ) validw[img * ROWQ + (i >> 6)] = vb;
}

// ---- K6a (truncated dense): suppression bit-matrix, rows < BPRE*64, chunks < BPRE (r13 verified) ----
__global__ void __launch_bounds__(256) k_iou(const float* __restrict__ srec,
                                             unsigned long long* __restrict__ mat) {
#pragma clang fp contract(off)
  int gb = blockIdx.x;
  int img = gb / 21;
  int g = gb % 21;
  int t, jcg;
  if (g < 6)       { t = 0; jcg = g; }
  else if (g < 11) { t = 1; jcg = g - 6; }
  else if (g < 15) { t = 2; jcg = g - 11; }
  else if (g < 18) { t = 3; jcg = g - 15; }
  else if (g < 20) { t = 4; jcg = g - 18; }
  else             { t = 5; jcg = g - 20; }
  int jcbase = (t + jcg) * 4;

  const int tid = threadIdx.x;
  const int i = t * 256 + tid;
  const float* sb = srec + (size_t)img * TOTC * 12;

  __shared__ float4 s_box[256];
  __shared__ float s_area[256];
  {
    int j = jcbase * 64 + tid;
    const float* r = sb + (size_t)j * 12;
    s_box[tid] = *(const float4*)r;
    s_area[tid] = r[4];
  }

  const float* rr = sb + (size_t)i * 12;
  float4 bb = *(const float4*)rr;
  float ix1 = bb.x, iy1 = bb.y, ix2 = bb.z, iy2 = bb.w;
  float ia = rr[4];
  __syncthreads();

  unsigned long long* rowp = mat + ((size_t)img * TOTC + (size_t)i) * ROWQ;
#pragma unroll
  for (int kk = 0; kk < 4; ++kk) {
    int jc = jcbase + kk;
    unsigned long long bits = 0ull;
    for (int b = 0; b < 64; ++b) {
      float4 jb = s_box[kk * 64 + b];
      float ja = s_area[kk * 64 + b];
      float ltx = fmaxf(ix1, jb.x), lty = fmaxf(iy1, jb.y);
      float rbx = fminf(ix2, jb.z), rby = fminf(iy2, jb.w);
      float w = fmaxf(rbx - ltx, 0.0f), h = fmaxf(rby - lty, 0.0f);
      float inter = w * h;
      float uni = (ia + ja) - inter;
      bool sup = (uni > 0.0f) && ((double)inter >= DM * (double)uni);
      if (sup) bits |= (1ull << b);
    }
    rowp[jc] = bits;
  }
}

// ---- K6b (8-wave, ONE barrier/iteration, replicated ballot-resolve).
// keepm is a deterministic pure function of (alive, diag word) -> ALL 8 waves compute it
// identically (each loads the diag word itself; same address -> L2 broadcast), removing
// the wave0->broadcast barrier. Double-buffered part[2][8] makes the single barrier
// WAR-safe (reads of slot B&1 precede barrier(B+1); next write to it follows barrier(B+1)).
// Greedy order, OR-set, and fallback semantics identical to the verified r16/r19 kernel.
__global__ void __launch_bounds__(512) k_resolve(const unsigned long long* __restrict__ mat,
                                                 const unsigned long long* __restrict__ validw,
                                                 const float* __restrict__ srec,
                                                 float* __restrict__ out) {
  const int img = blockIdx.x;
  const int tid = threadIdx.x;
  const int lane = tid & 63;
  const int wid = tid >> 6;  // 0..7
  const unsigned long long* matb = mat + (size_t)img * TOTC * ROWQ;
  const float* sb = srec + (size_t)img * TOTC * 12;
  float* ob = out + (size_t)img * POSTN * 4;
  float* os = out + (size_t)NIMG * POSTN * 4 + (size_t)img * POSTN;

  __shared__ int alist[1088];
  __shared__ unsigned long long vw[BPRE];
  __shared__ unsigned long long part[2][8];
  __shared__ int sh_nacc;
  __shared__ float kb[POSTN][5];  // fallback only

  for (int t = tid; t < BPRE; t += 512) vw[t] = validw[img * ROWQ + t];

  unsigned long long s0 = 0ull;
  int nacc = 0;

  // all waves hold the diagonal word (same address across waves -> cache broadcast)
  unsigned long long diagcur = matb[(size_t)lane * ROWQ + 0];
  __syncthreads();  // vw visible

  for (int B = 0; B < BPRE; ++B) {
    if (lane == B) part[B & 1][wid] = s0;
    __syncthreads();  // SINGLE barrier per iteration: partials visible

    unsigned long long supB = part[B & 1][0] | part[B & 1][1] | part[B & 1][2] | part[B & 1][3] |
                              part[B & 1][4] | part[B & 1][5] | part[B & 1][6] | part[B & 1][7];
    unsigned long long alive = vw[B] & ~supB;
    const int ibase = B * 64;

    // speculative loads: this wave's rank-mod-8 subset (<=8, named registers)
    unsigned long long m = alive;
    for (int t = 0; t < wid; ++t) if (m) m &= m - 1ull;
    auto popi = [&]() -> int {
      if (!m) return -1;
      int b = __builtin_ctzll(m);
      m &= m - 1ull;
#pragma unroll
      for (int t = 0; t < 7; ++t) if (m) m &= m - 1ull;
      return ibase + b;
    };
    int i0 = popi(), i1 = popi(), i2 = popi(), i3 = popi();
    int i4 = popi(), i5 = popi(), i6 = popi(), i7 = popi();
    unsigned long long r0 = 0, r1 = 0, r2 = 0, r3 = 0, r4 = 0, r5 = 0, r6 = 0, r7 = 0;
    bool lok = lane < BPRE;
    if (i0 >= 0 && lok) r0 = matb[(size_t)i0 * ROWQ + lane];
    if (i1 >= 0 && lok) r1 = matb[(size_t)i1 * ROWQ + lane];
    if (i2 >= 0 && lok) r2 = matb[(size_t)i2 * ROWQ + lane];
    if (i3 >= 0 && lok) r3 = matb[(size_t)i3 * ROWQ + lane];
    if (i4 >= 0 && lok) r4 = matb[(size_t)i4 * ROWQ + lane];
    if (i5 >= 0 && lok) r5 = matb[(size_t)i5 * ROWQ + lane];
    if (i6 >= 0 && lok) r6 = matb[(size_t)i6 * ROWQ + lane];
    if (i7 >= 0 && lok) r7 = matb[(size_t)i7 * ROWQ + lane];

    // next diagonal (all waves)
    unsigned long long diagnext = 0ull;
    int ibn = (B + 1) * 64 + lane;
    if (B + 1 < BPRE) diagnext = matb[(size_t)ibn * ROWQ + (B + 1)];

    // replicated ballot-resolve: identical keepm in every wave (deterministic)
    bool alv = ((alive >> lane) & 1ull) != 0ull;
    unsigned long long rem = alive, keepm = 0ull;
    while (rem) {
      int b = __builtin_ctzll(rem);
      keepm |= (1ull << b);
      bool sup = ((diagcur >> b) & 1ull) != 0ull;
      alv = alv && !sup;
      unsigned long long nb = __ballot(alv);
      rem = (b < 63) ? (nb & (~0ull << (b + 1))) : 0ull;
    }
    if (wid == 0 && ((keepm >> lane) & 1ull)) {
      int pos = nacc + __popcll(keepm & ((1ull << lane) - 1ull));
      alist[pos] = ibase + lane;
    }
    nacc += __popcll(keepm);
    if (nacc >= POSTN) break;

    // OR-update with own keepm (registers only, no barrier)
    if (i0 >= 0 && ((keepm >> (i0 - ibase)) & 1ull)) s0 |= r0;
    if (i1 >= 0 && ((keepm >> (i1 - ibase)) & 1ull)) s0 |= r1;
    if (i2 >= 0 && ((keepm >> (i2 - ibase)) & 1ull)) s0 |= r2;
    if (i3 >= 0 && ((keepm >> (i3 - ibase)) & 1ull)) s0 |= r3;
    if (i4 >= 0 && ((keepm >> (i4 - ibase)) & 1ull)) s0 |= r4;
    if (i5 >= 0 && ((keepm >> (i5 - ibase)) & 1ull)) s0 |= r5;
    if (i6 >= 0 && ((keepm >> (i6 - ibase)) & 1ull)) s0 |= r6;
    if (i7 >= 0 && ((keepm >> (i7 - ibase)) & 1ull)) s0 |= r7;
    diagcur = diagnext;
  }

  __syncthreads();  // alist (wave0 writes) visible to all

  // ---- fallback: tail ranks via direct IoU (never taken for this input; correctness net) ----
  if (nacc < POSTN) {
    for (int k = tid; k < nacc; k += 512) {
      const float* rec = sb + (size_t)alist[k] * 12;
      kb[k][0] = rec[0]; kb[k][1] = rec[1]; kb[k][2] = rec[2]; kb[k][3] = rec[3]; kb[k][4] = rec[4];
    }
    __syncthreads();
    if (wid == 0) {
      int n = nacc;
      for (int r = BPRE * 64; r < TOTC && n < POSTN; ++r) {
        const float* rec = sb + (size_t)r * 12;
        float4 bx = *(const float4*)rec;
        float ra = rec[4];
        float kf = rec[5];
        bool sup = false;
        for (int j = lane; j < n; j += 64) {
          float ltx = fmaxf(bx.x, kb[j][0]), lty = fmaxf(bx.y, kb[j][1]);
          float rbx = fminf(bx.z, kb[j][2]), rby = fminf(bx.w, kb[j][3]);
          float w = fmaxf(rbx - ltx, 0.0f), h = fmaxf(rby - lty, 0.0f);
          float inter = w * h;
          float uni = (ra + kb[j][4]) - inter;
          if (uni > 0.0f && (double)inter >= DM * (double)uni) sup = true;
        }
        bool any = (__ballot(sup) != 0ull);
        if (kf > -0.5f && !any) {
          if (lane == 0) {
            alist[n] = r;
            kb[n][0] = bx.x; kb[n][1] = bx.y; kb[n][2] = bx.z; kb[n][3] = bx.w; kb[n][4] = ra;
          }
          asm volatile("s_waitcnt lgkmcnt(0)" ::: "memory");
          ++n;
        }
      }
      if (lane == 0) sh_nacc = n;
    }
    __syncthreads();
    nacc = sh_nacc;
  }

  __syncthreads();
  int nout = nacc < POSTN ? nacc : POSTN;
  for (int k = tid; k < POSTN; k += 512) {
    if (k < nout) {
      int i = alist[k];
      const float* rec = sb + (size_t)i * 12;
      ob[(size_t)k * 4 + 0] = rec[6];
      ob[(size_t)k * 4 + 1] = rec[7];
      ob[(size_t)k * 4 + 2] = rec[8];
      ob[(size_t)k * 4 + 3] = rec[9];
      os[k] = rec[5];
    } else {  // zero-pad (replaces the d_out memset dispatch)
      ob[(size_t)k * 4 + 0] = 0.0f;
      ob[(size_t)k * 4 + 1] = 0.0f;
      ob[(size_t)k * 4 + 2] = 0.0f;
      ob[(size_t)k * 4 + 3] = 0.0f;
      os[k] = 0.0f;
    }
  }
}

extern "C" void kernel_launch(void* const* d_in, const int* in_sizes, int n_in,
                              void* d_out, int out_size, void* d_ws, size_t ws_size,
                              hipStream_t stream) {
  const float* obj = (const float*)d_in[0];
  const float* del = (const float*)d_in[1];
  const float* anc = (const float*)d_in[2];
  float* out = (float*)d_out;

  char* w = (char*)d_ws;
  size_t o = 0;
  auto carve = [&](size_t bytes) -> char* {
    char* p = w + o;
    o = (o + bytes + 255) & ~(size_t)255;
    return p;
  };
  int* cand = (int*)carve((size_t)NIMG * TOTC * 4);
  unsigned* skey = (unsigned*)carve((size_t)NIMG * TOTC * 4);
  float* keyf = (float*)carve((size_t)NIMG * TOTC * 4);
  int* ord = (int*)carve((size_t)NIMG * TOTC * 4);
  float* boxo = (float*)carve((size_t)NIMG * TOTC * 16);
  float* srec = (float*)carve((size_t)NIMG * TOTC * 48);
  unsigned* maxcb = (unsigned*)carve(64);
  unsigned* hist = (unsigned*)carve((size_t)64 * 256 * 4);
  unsigned* thr = (unsigned*)carve((size_t)64 * 2 * 4);
  unsigned* cnt = (unsigned*)carve((size_t)64 * 2 * 4);
  int* eqbuf = (int*)carve((size_t)64 * EQCAP * 4);
  unsigned long long* validw = (unsigned long long*)carve((size_t)NIMG * ROWQ * 8);
  unsigned long long* mat = (unsigned long long*)carve((size_t)NIMG * TOTC * ROWQ * 8);

  k_zero<<<64, 256, 0, stream>>>(hist, cnt, maxcb);
  k_hist<<<16 * 64, 256, 0, stream>>>(obj, hist);
  k_thresh<<<64, 64, 0, stream>>>(hist, thr);
  k_emit<<<16 * 65, 256, 0, stream>>>(obj, thr, cand, eqbuf, cnt);
  k_refine<<<64, 256, 0, stream>>>(obj, thr, eqbuf, cnt, cand);
  k_lvlsort<<<80, 1024, 0, stream>>>(obj, cand);
  k_decode<<<dim3(16, (TOTC + 255) / 256), 256, 0, stream>>>(obj, del, anc, cand, boxo, keyf, skey, maxcb);
  k_rank<<<16 * 19, 256, 0, stream>>>(skey, ord);
  k_srec<<<dim3(16, (TOTC + 255) / 256), 256, 0, stream>>>(boxo, keyf, ord, maxcb, srec, validw);
  k_iou<<<16 * 21, 256, 0, stream>>>(srec, mat);
  k_resolve<<<16, 512, 0, stream>>>(mat, validw, srec, out);
}

// Round 21
// 311.198 us; speedup vs baseline: 1.0852x; 1.0852x over previous
//
#include <hip/hip_runtime.h>
#include <stdint.h>

#define NIMG 16
#define ATOT 261888
#define TOTC 4768
#define POSTN 1000
#define ROWQ 75   // qwords per suppression-matrix row (4768 bits -> 75)
#define EQCAP 8192
#define SCAP 1088  // LDS staging capacity per k_emit block (max real count ~950)
#define BPRE 24    // matrix truncation: rows < BPRE*64, col-chunks < BPRE (resolve stops at B~18)
// Exact div-free NMS predicate: RN(inter/uni) > 0.7f  <=>  inter >= DM*uni (doubles exact).
// DM = midpoint(0.7f, nextafterf(0.7f)); tie rounds to even (0x3F333334 > 0.7f) -> use >=.
#define DM 0.7000000178813934326171875

__device__ __forceinline__ unsigned sortable_u32(float f) {
  unsigned b = __float_as_uint(f);
  return (b & 0x80000000u) ? ~b : (b | 0x80000000u);
}

// ---- XLA CPU expf replica (Cephes constants, FMA as vsl.MulAdd)  [VERIFIED absmax 0.0] ----
__device__ __forceinline__ float exp_xla(float x) {
  float xc = fminf(x, 88.72283935546875f);
  xc = fmaxf(xc, -87.33654022216796875f);
  float n = floorf(fmaf(xc, 1.44269504088896341f, 0.5f));
  float r = fmaf(n, -0.693359375f, xc);
  r = fmaf(n, 2.12194440e-4f, r);
  float y = 1.9875691500e-4f;
  y = fmaf(y, r, 1.3981999507e-3f);
  y = fmaf(y, r, 8.3334519073e-3f);
  y = fmaf(y, r, 4.1665795894e-2f);
  y = fmaf(y, r, 1.6666665459e-1f);
  y = fmaf(y, r, 5.0000001201e-1f);
  float r2 = r * r;
  y = fmaf(y, r2, r);
  y = y + 1.0f;
  return ldexpf(y, (int)n);
}

__device__ __forceinline__ float sigmoid_ref(float x) {
#pragma clang fp contract(off)
  float e = exp_xla(-x);
  return 1.0f / (1.0f + e);
}

// Fine chunk mapping: 64 chunks of <=4096 elements per image over levels 0..3.
__device__ __forceinline__ void chunk_map4k(int c, int& lvl, int& start, int& cnt) {
  if (c < 48)      { lvl = 0; start = c * 4096;        cnt = 4096; }
  else if (c < 60) { lvl = 1; start = (c - 48) * 4096; cnt = 4096; }
  else if (c < 63) { lvl = 2; start = (c - 60) * 4096; cnt = 4096; }
  else             { lvl = 3; start = 0;               cnt = 3072; }
}
__constant__ int d_LO[5] = {0, 196608, 245760, 258048, 261120};
__constant__ int d_CO[5] = {0, 1000, 2000, 3000, 4000};

// ---- S0: zero hist/cnt/maxcb in one dispatch (replaces 3 hipMemsetAsync) ----
__global__ void __launch_bounds__(256) k_zero(unsigned* __restrict__ hist,
                                              unsigned* __restrict__ cnt,
                                              unsigned* __restrict__ maxcb) {
  int i = blockIdx.x * 256 + threadIdx.x;  // 64 blocks x 256 = 16384 = hist size
  hist[i] = 0;
  if (i < 128) cnt[i] = 0;
  if (i < 16) maxcb[i] = 0;
}

// ---- S1: per-(img,lvl) 256-bin histogram of top-8 sortable bits ----
__global__ void __launch_bounds__(256) k_hist(const float* __restrict__ obj,
                                              unsigned* __restrict__ hist) {
  int img = blockIdx.x >> 6, c = blockIdx.x & 63;
  int lvl, start, cnt;
  chunk_map4k(c, lvl, start, cnt);
  const float4* p4 = (const float4*)(obj + (size_t)img * ATOT + d_LO[lvl] + start);
  __shared__ unsigned h[256];
  h[threadIdx.x] = 0;
  __syncthreads();
  int nv = cnt >> 2;
  for (int i = threadIdx.x; i < nv; i += 256) {
    float4 v = p4[i];
    atomicAdd(&h[sortable_u32(v.x) >> 24], 1u);
    atomicAdd(&h[sortable_u32(v.y) >> 24], 1u);
    atomicAdd(&h[sortable_u32(v.z) >> 24], 1u);
    atomicAdd(&h[sortable_u32(v.w) >> 24], 1u);
  }
  __syncthreads();
  unsigned* gh = hist + (img * 4 + lvl) * 256;
  if (h[threadIdx.x]) atomicAdd(&gh[threadIdx.x], h[threadIdx.x]);
}

// ---- S2: per-(img,lvl) threshold bucket d0 + krem ----
__global__ void __launch_bounds__(64) k_thresh(const unsigned* __restrict__ hist,
                                               unsigned* __restrict__ thr) {
  int il = blockIdx.x;
  if (threadIdx.x != 0) return;
  const unsigned* h = hist + il * 256;
  unsigned krem = 1000, cum = 0;
  int d = 255;
  for (; d > 0; --d) {
    if (cum + h[d] >= krem) break;
    cum += h[d];
  }
  thr[il * 2] = (unsigned)d;
  thr[il * 2 + 1] = krem - cum;
}

// ---- S3: emit via LDS compaction + per-block bulk reservation (verified r11) ----
__global__ void __launch_bounds__(256) k_emit(const float* __restrict__ obj,
                                              const unsigned* __restrict__ thr,
                                              int* __restrict__ cand,
                                              int* __restrict__ eqbuf,
                                              unsigned* __restrict__ cnt) {
  int img = blockIdx.x / 65, c = blockIdx.x % 65;
  if (c == 64) {
    for (int i = threadIdx.x; i < 768; i += 256)
      cand[img * TOTC + d_CO[4] + i] = d_LO[4] + i;
    return;
  }
  int lvl, start, cntn;
  chunk_map4k(c, lvl, start, cntn);
  int il = img * 4 + lvl;
  unsigned d0 = thr[il * 2];
  int gbase = d_LO[lvl] + start;
  const float4* p4 = (const float4*)(obj + (size_t)img * ATOT + gbase);
  int nv = cntn >> 2;
  int cbase = img * TOTC + d_CO[lvl];

  __shared__ int gts[SCAP], eqs[SCAP];
  __shared__ int nGt, nEq, gtBase, eqBase;
  if (threadIdx.x == 0) { nGt = 0; nEq = 0; }
  __syncthreads();

  float4 v[4];
  int ni = 0;
#pragma unroll
  for (int k = 0; k < 4; ++k) {
    int i = threadIdx.x + k * 256;
    if (i < nv) { v[k] = p4[i]; ni = k + 1; }
  }
#pragma unroll
  for (int k = 0; k < 4; ++k) {
    if (k >= ni) break;
    float vv[4] = {v[k].x, v[k].y, v[k].z, v[k].w};
#pragma unroll
    for (int c4 = 0; c4 < 4; ++c4) {
      unsigned u = sortable_u32(vv[c4]);
      unsigned d = u >> 24;
      if (d >= d0) {
        int gidx = gbase + (threadIdx.x + k * 256) * 4 + c4;
        if (d > d0) {
          int p = atomicAdd(&nGt, 1);
          if (p < SCAP) gts[p] = gidx;
          else { int s = (int)atomicAdd(&cnt[il * 2], 1u); cand[cbase + s] = gidx; }
        } else {
          int p = atomicAdd(&nEq, 1);
          if (p < SCAP) eqs[p] = gidx;
          else { int e = (int)atomicAdd(&cnt[il * 2 + 1], 1u); if (e < EQCAP) eqbuf[il * EQCAP + e] = gidx; }
        }
      }
    }
  }
  __syncthreads();
  int ng = nGt < SCAP ? nGt : SCAP;
  int ne = nEq < SCAP ? nEq : SCAP;
  if (threadIdx.x == 0) {
    gtBase = (int)atomicAdd(&cnt[il * 2], (unsigned)ng);
    eqBase = (int)atomicAdd(&cnt[il * 2 + 1], (unsigned)ne);
  }
  __syncthreads();
  for (int k = threadIdx.x; k < ng; k += 256) cand[cbase + gtBase + k] = gts[k];
  for (int k = threadIdx.x; k < ne; k += 256) {
    int e = eqBase + k;
    if (e < EQCAP) eqbuf[il * EQCAP + e] = eqs[k];
  }
}

// ---- S4: refine eq-bucket with radix rounds 1-3 ----
__global__ void __launch_bounds__(256) k_refine(const float* __restrict__ obj,
                                                const unsigned* __restrict__ thr,
                                                const int* __restrict__ eqbuf,
                                                const unsigned* __restrict__ cnt,
                                                int* __restrict__ cand) {
  int il = blockIdx.x;
  int img = il >> 2, lvl = il & 3;
  unsigned pref = thr[il * 2];
  unsigned krem = thr[il * 2 + 1];
  int neq = min((int)cnt[il * 2 + 1], EQCAP);
  int cgt = (int)cnt[il * 2];
  const float* p = obj + (size_t)img * ATOT;
  const int* eq = eqbuf + il * EQCAP;
  int cbase = img * TOTC + d_CO[lvl];
  __shared__ unsigned h[256];
  __shared__ unsigned s_pref, s_krem;
  for (int round = 1; round < 4; ++round) {
    int shift = 24 - 8 * round;
    h[threadIdx.x] = 0;
    __syncthreads();
    for (int e = threadIdx.x; e < neq; e += 256) {
      unsigned u = sortable_u32(p[eq[e]]);
      if ((u >> (shift + 8)) == pref) atomicAdd(&h[(u >> shift) & 255u], 1u);
    }
    __syncthreads();
    if (threadIdx.x == 0) {
      unsigned cum = 0;
      int d = 255;
      for (; d > 0; --d) {
        if (cum + h[d] >= krem) break;
        cum += h[d];
      }
      s_pref = (pref << 8) | (unsigned)d;
      s_krem = krem - cum;
    }
    __syncthreads();
    pref = s_pref;
    krem = s_krem;
    __syncthreads();
  }
  __shared__ int cg2, ce2;
  __shared__ int eqi[1024];
  if (threadIdx.x == 0) { cg2 = 0; ce2 = 0; }
  __syncthreads();
  for (int e = threadIdx.x; e < neq; e += 256) {
    int gidx = eq[e];
    unsigned u = sortable_u32(p[gidx]);
    if (u > pref) {
      int s = atomicAdd(&cg2, 1);
      cand[cbase + cgt + s] = gidx;
    } else if (u == pref) {
      int s2 = atomicAdd(&ce2, 1);
      if (s2 < 1024) eqi[s2] = gidx;
    }
  }
  __syncthreads();
  if (threadIdx.x == 0) {
    int ne = ce2 < 1024 ? ce2 : 1024;
    int base = cgt + cg2;
    for (int r = 0; r < (int)krem; ++r) {
      int besti = -1, bestv = 0x7fffffff;
      for (int e2 = 0; e2 < ne; ++e2) {
        int v = eqi[e2];
        if (v >= 0 && v < bestv) { bestv = v; besti = e2; }
      }
      if (besti < 0) break;
      eqi[besti] = -1;
      cand[cbase + base + r] = bestv;
    }
  }
}

// ---- K2: sort each level's selected slots by (obj desc, idx asc) ----
__global__ void __launch_bounds__(1024) k_lvlsort(const float* __restrict__ obj,
                                                  int* __restrict__ cand) {
  const int KL[5] = {1000, 1000, 1000, 1000, 768};
  const int CO[5] = {0, 1000, 2000, 3000, 4000};
  int img = blockIdx.x / 5, lvl = blockIdx.x % 5;
  int k = KL[lvl];
  int cbase = img * TOTC + CO[lvl];
  int tid = threadIdx.x;
  __shared__ unsigned long long sh[1024];
  unsigned long long key = 0ull;
  if (tid < k) {
    int idx = cand[cbase + tid];
    unsigned u = sortable_u32(obj[(size_t)img * ATOT + idx]);
    key = ((unsigned long long)u << 32) | (unsigned)(0xFFFFFFFFu - (unsigned)idx);
  }
  sh[tid] = key;
  __syncthreads();
  for (int kk = 2; kk <= 1024; kk <<= 1)
    for (int j = kk >> 1; j > 0; j >>= 1) {
      int ixj = tid ^ j;
      if (ixj > tid) {
        unsigned long long a = sh[tid], b = sh[ixj];
        bool up2 = ((tid & kk) == 0);
        if ((a < b) == up2) { sh[tid] = b; sh[ixj] = a; }
      }
      __syncthreads();
    }
  if (tid < k) {
    unsigned low = (unsigned)(sh[tid] & 0xFFFFFFFFull);
    cand[cbase + tid] = (int)(0xFFFFFFFFu - low);
  }
}

// ---- K3: gather + sigmoid + BoxCoder decode + clip + valid; per-image max coord ----
__global__ void __launch_bounds__(256) k_decode(const float* __restrict__ obj,
                                                const float* __restrict__ del,
                                                const float* __restrict__ anc,
                                                const int* __restrict__ cand,
                                                float* __restrict__ boxo,
                                                float* __restrict__ keyf,
                                                unsigned* __restrict__ skey,
                                                unsigned* __restrict__ maxcb) {
#pragma clang fp contract(off)
  int img = blockIdx.x;
  int c = blockIdx.y * 256 + threadIdx.x;
  float m = 0.0f;
  if (c < TOTC) {
    int a = cand[img * TOTC + c];
    float o = obj[(size_t)img * ATOT + a];
    float s = sigmoid_ref(o);
    const float* ap = anc + (size_t)a * 4;
    float a0 = ap[0], a1 = ap[1], a2 = ap[2], a3 = ap[3];
    const float* dp = del + ((size_t)img * ATOT + (size_t)a) * 4;
    float dx = dp[0], dy = dp[1], dw = dp[2], dh = dp[3];
    float wa = a2 - a0, ha = a3 - a1;
    float cxa = a0 + 0.5f * wa, cya = a1 + 0.5f * ha;
    dw = fminf(dw, 4.135166556742356f);
    dh = fminf(dh, 4.135166556742356f);
    float cx = dx * wa + cxa;
    float cy = dy * ha + cya;
    float w = exp_xla(dw) * wa;
    float h = exp_xla(dh) * ha;
    float x1 = cx - 0.5f * w, y1 = cy - 0.5f * h;
    float x2 = cx + 0.5f * w, y2 = cy + 0.5f * h;
    x1 = fminf(fmaxf(x1, 0.0f), 1024.0f);
    x2 = fminf(fmaxf(x2, 0.0f), 1024.0f);
    y1 = fminf(fmaxf(y1, 0.0f), 1024.0f);
    y2 = fminf(fmaxf(y2, 0.0f), 1024.0f);
    float ww = x2 - x1, hh = y2 - y1;
    bool valid = (ww >= 1e-3f) && (hh >= 1e-3f) && (s >= 0.0f);
    float kf = valid ? s : -1.0f;
    float4 bx = make_float4(x1, y1, x2, y2);
    *(float4*)(boxo + (size_t)(img * TOTC + c) * 4) = bx;
    keyf[img * TOTC + c] = kf;
    skey[img * TOTC + c] = sortable_u32(kf);
    m = fmaxf(fmaxf(x1, x2), fmaxf(y1, y2));
  }
  __shared__ float red[256];
  red[threadIdx.x] = m;
  __syncthreads();
  for (int s2 = 128; s2 > 0; s2 >>= 1) {
    if (threadIdx.x < s2) red[threadIdx.x] = fmaxf(red[threadIdx.x], red[threadIdx.x + s2]);
    __syncthreads();
  }
  if (threadIdx.x == 0) atomicMax(&maxcb[img], __float_as_uint(red[0]));
}

// ---- K4 (rank-by-count): ord[rank] = slot (verified r15) ----
__global__ void __launch_bounds__(256) k_rank(const unsigned* __restrict__ skey,
                                              int* __restrict__ ord) {
  int img = blockIdx.x / 19;
  int tile = blockIdx.x % 19;
  __shared__ unsigned long long keys[TOTC];
  const unsigned* sk = skey + img * TOTC;
  for (int k = threadIdx.x; k < TOTC; k += 256)
    keys[k] = ((unsigned long long)sk[k] << 16) | (unsigned)(0xFFFF - k);
  __syncthreads();
  int i = tile * 256 + threadIdx.x;
  if (i >= TOTC) return;
  unsigned long long my = keys[i];
  int cnt = 0;
  int j = 0;
  for (; j + 8 <= TOTC; j += 8) {
#pragma unroll
    for (int u = 0; u < 8; ++u) cnt += (keys[j + u] > my) ? 1 : 0;
  }
  for (; j < TOTC; ++j) cnt += (keys[j] > my) ? 1 : 0;
  ord[img * TOTC + cnt] = i;
}

// ---- K5: build sorted records + validw (rank-space ballot) ----
__global__ void __launch_bounds__(256) k_srec(const float* __restrict__ boxo,
                                              const float* __restrict__ keyf,
                                              const int* __restrict__ ord,
                                              const unsigned* __restrict__ maxcb,
                                              float* __restrict__ srec,
                                              unsigned long long* __restrict__ validw) {
#pragma clang fp contract(off)
  int img = blockIdx.x;
  int i = blockIdx.y * 256 + threadIdx.x;
  if (i >= TOTC) return;
  int p = ord[img * TOTC + i];
  int lvl = p / 1000;
  if (lvl > 4) lvl = 4;
  float4 b = *(const float4*)(boxo + (size_t)(img * TOTC + p) * 4);
  float maxc = __uint_as_float(maxcb[img]);
  float off = (float)lvl * (maxc + 1.0f);
  float ox1 = b.x + off, oy1 = b.y + off, ox2 = b.z + off, oy2 = b.w + off;
  float area = (ox2 - ox1) * (oy2 - oy1);
  float kf = keyf[img * TOTC + p];
  float* r = srec + (size_t)(img * TOTC + i) * 12;
  r[0] = ox1; r[1] = oy1; r[2] = ox2; r[3] = oy2;
  r[4] = area; r[5] = kf;
  r[6] = b.x; r[7] = b.y; r[8] = b.z; r[9] = b.w;
  r[10] = __int_as_float(lvl); r[11] = 0.0f;
  bool valid = kf > -0.5f;
  unsigned long long vb = __ballot(valid);
  if ((threadIdx.x & 63) == 0 && (i >> 6) < ROWQ) validw[img * ROWQ + (i >> 6)] = vb;
}

// ---- K6a (truncated dense): suppression bit-matrix, rows < BPRE*64, chunks < BPRE (r13 verified) ----
__global__ void __launch_bounds__(256) k_iou(const float* __restrict__ srec,
                                             unsigned long long* __restrict__ mat) {
#pragma clang fp contract(off)
  int gb = blockIdx.x;
  int img = gb / 21;
  int g = gb % 21;
  int t, jcg;
  if (g < 6)       { t = 0; jcg = g; }
  else if (g < 11) { t = 1; jcg = g - 6; }
  else if (g < 15) { t = 2; jcg = g - 11; }
  else if (g < 18) { t = 3; jcg = g - 15; }
  else if (g < 20) { t = 4; jcg = g - 18; }
  else             { t = 5; jcg = g - 20; }
  int jcbase = (t + jcg) * 4;

  const int tid = threadIdx.x;
  const int i = t * 256 + tid;
  const float* sb = srec + (size_t)img * TOTC * 12;

  __shared__ float4 s_box[256];
  __shared__ float s_area[256];
  {
    int j = jcbase * 64 + tid;
    const float* r = sb + (size_t)j * 12;
    s_box[tid] = *(const float4*)r;
    s_area[tid] = r[4];
  }

  const float* rr = sb + (size_t)i * 12;
  float4 bb = *(const float4*)rr;
  float ix1 = bb.x, iy1 = bb.y, ix2 = bb.z, iy2 = bb.w;
  float ia = rr[4];
  __syncthreads();

  unsigned long long* rowp = mat + ((size_t)img * TOTC + (size_t)i) * ROWQ;
#pragma unroll
  for (int kk = 0; kk < 4; ++kk) {
    int jc = jcbase + kk;
    unsigned long long bits = 0ull;
    for (int b = 0; b < 64; ++b) {
      float4 jb = s_box[kk * 64 + b];
      float ja = s_area[kk * 64 + b];
      float ltx = fmaxf(ix1, jb.x), lty = fmaxf(iy1, jb.y);
      float rbx = fminf(ix2, jb.z), rby = fminf(iy2, jb.w);
      float w = fmaxf(rbx - ltx, 0.0f), h = fmaxf(rby - lty, 0.0f);
      float inter = w * h;
      float uni = (ia + ja) - inter;
      bool sup = (uni > 0.0f) && ((double)inter >= DM * (double)uni);
      if (sup) bits |= (1ull << b);
    }
    rowp[jc] = bits;
  }
}

// ---- K6b (8-wave, named-register speculative prefetch, ballot-resolve; verified r16/r19).
// Epilogue writes the FULL per-image output region (zeros beyond nout).
__global__ void __launch_bounds__(512) k_resolve(const unsigned long long* __restrict__ mat,
                                                 const unsigned long long* __restrict__ validw,
                                                 const float* __restrict__ srec,
                                                 float* __restrict__ out) {
  const int img = blockIdx.x;
  const int tid = threadIdx.x;
  const int lane = tid & 63;
  const int wid = tid >> 6;  // 0..7
  const unsigned long long* matb = mat + (size_t)img * TOTC * ROWQ;
  const float* sb = srec + (size_t)img * TOTC * 12;
  float* ob = out + (size_t)img * POSTN * 4;
  float* os = out + (size_t)NIMG * POSTN * 4 + (size_t)img * POSTN;

  __shared__ int alist[1088];
  __shared__ unsigned long long vw[BPRE];
  __shared__ unsigned long long part[2][8];
  __shared__ unsigned long long sh_keep;
  __shared__ int sh_nacc;
  __shared__ float kb[POSTN][5];  // fallback only

  for (int t = tid; t < BPRE; t += 512) vw[t] = validw[img * ROWQ + t];

  unsigned long long s0 = 0ull;
  int nacc = 0;

  unsigned long long diagcur = 0ull;
  if (wid == 0) diagcur = matb[(size_t)lane * ROWQ + 0];
  __syncthreads();

  for (int B = 0; B < BPRE; ++B) {
    if (lane == B) part[B & 1][wid] = s0;
    __syncthreads();  // b1: partials visible

    unsigned long long supB = part[B & 1][0] | part[B & 1][1] | part[B & 1][2] | part[B & 1][3] |
                              part[B & 1][4] | part[B & 1][5] | part[B & 1][6] | part[B & 1][7];
    unsigned long long alive = vw[B] & ~supB;
    const int ibase = B * 64;

    unsigned long long m = alive;
    for (int t = 0; t < wid; ++t) if (m) m &= m - 1ull;
    auto popi = [&]() -> int {
      if (!m) return -1;
      int b = __builtin_ctzll(m);
      m &= m - 1ull;
#pragma unroll
      for (int t = 0; t < 7; ++t) if (m) m &= m - 1ull;
      return ibase + b;
    };
    int i0 = popi(), i1 = popi(), i2 = popi(), i3 = popi();
    int i4 = popi(), i5 = popi(), i6 = popi(), i7 = popi();
    unsigned long long r0 = 0, r1 = 0, r2 = 0, r3 = 0, r4 = 0, r5 = 0, r6 = 0, r7 = 0;
    bool lok = lane < BPRE;
    if (i0 >= 0 && lok) r0 = matb[(size_t)i0 * ROWQ + lane];
    if (i1 >= 0 && lok) r1 = matb[(size_t)i1 * ROWQ + lane];
    if (i2 >= 0 && lok) r2 = matb[(size_t)i2 * ROWQ + lane];
    if (i3 >= 0 && lok) r3 = matb[(size_t)i3 * ROWQ + lane];
    if (i4 >= 0 && lok) r4 = matb[(size_t)i4 * ROWQ + lane];
    if (i5 >= 0 && lok) r5 = matb[(size_t)i5 * ROWQ + lane];
    if (i6 >= 0 && lok) r6 = matb[(size_t)i6 * ROWQ + lane];
    if (i7 >= 0 && lok) r7 = matb[(size_t)i7 * ROWQ + lane];

    unsigned long long diagnext = 0ull;
    if (wid == 0) {
      int ibn = (B + 1) * 64 + lane;
      if (B + 1 < BPRE) diagnext = matb[(size_t)ibn * ROWQ + (B + 1)];
      bool alv = ((alive >> lane) & 1ull) != 0ull;
      unsigned long long rem = alive, keepm = 0ull;
      while (rem) {
        int b = __builtin_ctzll(rem);
        keepm |= (1ull << b);
        bool sup = ((diagcur >> b) & 1ull) != 0ull;
        alv = alv && !sup;
        unsigned long long nb = __ballot(alv);
        rem = (b < 63) ? (nb & (~0ull << (b + 1))) : 0ull;
      }
      if (lane == 0) sh_keep = keepm;
      if ((keepm >> lane) & 1ull) {
        int pos = nacc + __popcll(keepm & ((1ull << lane) - 1ull));
        alist[pos] = ibase + lane;
      }
    }
    __syncthreads();  // b2: keepm/alist visible; drains speculative loads
    unsigned long long keepm = sh_keep;
    nacc += __popcll(keepm);
    if (nacc >= POSTN) break;

    if (i0 >= 0 && ((keepm >> (i0 - ibase)) & 1ull)) s0 |= r0;
    if (i1 >= 0 && ((keepm >> (i1 - ibase)) & 1ull)) s0 |= r1;
    if (i2 >= 0 && ((keepm >> (i2 - ibase)) & 1ull)) s0 |= r2;
    if (i3 >= 0 && ((keepm >> (i3 - ibase)) & 1ull)) s0 |= r3;
    if (i4 >= 0 && ((keepm >> (i4 - ibase)) & 1ull)) s0 |= r4;
    if (i5 >= 0 && ((keepm >> (i5 - ibase)) & 1ull)) s0 |= r5;
    if (i6 >= 0 && ((keepm >> (i6 - ibase)) & 1ull)) s0 |= r6;
    if (i7 >= 0 && ((keepm >> (i7 - ibase)) & 1ull)) s0 |= r7;
    if (wid == 0) diagcur = diagnext;
  }

  // ---- fallback: tail ranks via direct IoU (never taken for this input; correctness net) ----
  if (nacc < POSTN) {
    for (int k = tid; k < nacc; k += 512) {
      const float* rec = sb + (size_t)alist[k] * 12;
      kb[k][0] = rec[0]; kb[k][1] = rec[1]; kb[k][2] = rec[2]; kb[k][3] = rec[3]; kb[k][4] = rec[4];
    }
    __syncthreads();
    if (wid == 0) {
      int n = nacc;
      for (int r = BPRE * 64; r < TOTC && n < POSTN; ++r) {
        const float* rec = sb + (size_t)r * 12;
        float4 bx = *(const float4*)rec;
        float ra = rec[4];
        float kf = rec[5];
        bool sup = false;
        for (int j = lane; j < n; j += 64) {
          float ltx = fmaxf(bx.x, kb[j][0]), lty = fmaxf(bx.y, kb[j][1]);
          float rbx = fminf(bx.z, kb[j][2]), rby = fminf(bx.w, kb[j][3]);
          float w = fmaxf(rbx - ltx, 0.0f), h = fmaxf(rby - lty, 0.0f);
          float inter = w * h;
          float uni = (ra + kb[j][4]) - inter;
          if (uni > 0.0f && (double)inter >= DM * (double)uni) sup = true;
        }
        bool any = (__ballot(sup) != 0ull);
        if (kf > -0.5f && !any) {
          if (lane == 0) {
            alist[n] = r;
            kb[n][0] = bx.x; kb[n][1] = bx.y; kb[n][2] = bx.z; kb[n][3] = bx.w; kb[n][4] = ra;
          }
          asm volatile("s_waitcnt lgkmcnt(0)" ::: "memory");
          ++n;
        }
      }
      if (lane == 0) sh_nacc = n;
    }
    __syncthreads();
    nacc = sh_nacc;
  }

  __syncthreads();
  int nout = nacc < POSTN ? nacc : POSTN;
  for (int k = tid; k < POSTN; k += 512) {
    if (k < nout) {
      int i = alist[k];
      const float* rec = sb + (size_t)i * 12;
      ob[(size_t)k * 4 + 0] = rec[6];
      ob[(size_t)k * 4 + 1] = rec[7];
      ob[(size_t)k * 4 + 2] = rec[8];
      ob[(size_t)k * 4 + 3] = rec[9];
      os[k] = rec[5];
    } else {  // zero-pad (replaces the d_out memset dispatch)
      ob[(size_t)k * 4 + 0] = 0.0f;
      ob[(size_t)k * 4 + 1] = 0.0f;
      ob[(size_t)k * 4 + 2] = 0.0f;
      ob[(size_t)k * 4 + 3] = 0.0f;
      os[k] = 0.0f;
    }
  }
}

extern "C" void kernel_launch(void* const* d_in, const int* in_sizes, int n_in,
                              void* d_out, int out_size, void* d_ws, size_t ws_size,
                              hipStream_t stream) {
  const float* obj = (const float*)d_in[0];
  const float* del = (const float*)d_in[1];
  const float* anc = (const float*)d_in[2];
  float* out = (float*)d_out;

  char* w = (char*)d_ws;
  size_t o = 0;
  auto carve = [&](size_t bytes) -> char* {
    char* p = w + o;
    o = (o + bytes + 255) & ~(size_t)255;
    return p;
  };
  int* cand = (int*)carve((size_t)NIMG * TOTC * 4);
  unsigned* skey = (unsigned*)carve((size_t)NIMG * TOTC * 4);
  float* keyf = (float*)carve((size_t)NIMG * TOTC * 4);
  int* ord = (int*)carve((size_t)NIMG * TOTC * 4);
  float* boxo = (float*)carve((size_t)NIMG * TOTC * 16);
  float* srec = (float*)carve((size_t)NIMG * TOTC * 48);
  unsigned* maxcb = (unsigned*)carve(64);
  unsigned* hist = (unsigned*)carve((size_t)64 * 256 * 4);
  unsigned* thr = (unsigned*)carve((size_t)64 * 2 * 4);
  unsigned* cnt = (unsigned*)carve((size_t)64 * 2 * 4);
  int* eqbuf = (int*)carve((size_t)64 * EQCAP * 4);
  unsigned long long* validw = (unsigned long long*)carve((size_t)NIMG * ROWQ * 8);
  unsigned long long* mat = (unsigned long long*)carve((size_t)NIMG * TOTC * ROWQ * 8);

  k_zero<<<64, 256, 0, stream>>>(hist, cnt, maxcb);
  k_hist<<<16 * 64, 256, 0, stream>>>(obj, hist);
  k_thresh<<<64, 64, 0, stream>>>(hist, thr);
  k_emit<<<16 * 65, 256, 0, stream>>>(obj, thr, cand, eqbuf, cnt);
  k_refine<<<64, 256, 0, stream>>>(obj, thr, eqbuf, cnt, cand);
  k_lvlsort<<<80, 1024, 0, stream>>>(obj, cand);
  k_decode<<<dim3(16, (TOTC + 255) / 256), 256, 0, stream>>>(obj, del, anc, cand, boxo, keyf, skey, maxcb);
  k_rank<<<16 * 19, 256, 0, stream>>>(skey, ord);
  k_srec<<<dim3(16, (TOTC + 255) / 256), 256, 0, stream>>>(boxo, keyf, ord, maxcb, srec, validw);
  k_iou<<<16 * 21, 256, 0, stream>>>(srec, mat);
  k_resolve<<<16, 512, 0, stream>>>(mat, validw, srec, out);
}